// Round 11
// baseline (7427.406 us; speedup 1.0000x reference)
//
#include <hip/hip_runtime.h>
#include <stdint.h>

// CosineSimilarityCodebook: X[16384,256] f32, EMB[8192,256] f32 (re-l2norm'd).
// out = [quantized 16384*256 f32][indices 16384 as f32]
// R11: R9 two-pass rescue with the pass1 cross-wave WRITE RACE fixed:
//   waves (wy,wx=0/1) share rows; R9 had both plain-storing partB[row][split].
//   Now merged exactly via dedicated LDS (kx/sx) before a single store.
//   pass1: hh-only f16 MFMA GEMM-argmax with top-2 tracking (1/3 MFMA work).
//   merge: margin test (2B = 2.5e-3*||x||, rigorous); close rows -> rescue list.
//   pass2: proven 3-term split-f16 body (absmax 0.0 x4) on rescued rows only.
// Tier-2 fallback: R8 single-pass 3-term (proven). Tier-3: R4 in-loop split.

#define M_ROWS 16384
#define KCODES 8192
#define DDIM   256

#define BR   128
#define BCC  128
#define BK   32
#define NSPLIT 8
#define CPS  (KCODES / NSPLIT)              // 1024
#define NSLICE ((CPS / BCC) * (DDIM / BK))  // 64
#define LSCALE     512.0f
#define INV_LSCALE (1.0f / 512.0f)
#define TILE_H 4096
#define MARGIN_COEF 2.5e-3f                  // 2B per unit ||x||  (>=25% headroom)

// pass2 geometry
#define BR2     64
#define NSPLIT2 16
#define CPS2    (KCODES / NSPLIT2)           // 512
#define NSLICE2 ((CPS2 / BCC) * (DDIM / BK)) // 32

typedef _Float16 half4v __attribute__((ext_vector_type(4)));
typedef _Float16 half8v __attribute__((ext_vector_type(8)));
typedef float    f32x4  __attribute__((ext_vector_type(4)));

__device__ __forceinline__ unsigned int fkey(float f) {
    unsigned int u = __float_as_uint(f);
    return (u & 0x80000000u) ? ~u : (u | 0x80000000u);
}
__device__ __forceinline__ float fkey_dec(unsigned long long k) {
    unsigned int u = (unsigned int)(k >> 32);
    unsigned int b = (u & 0x80000000u) ? (u ^ 0x80000000u) : ~u;
    return __uint_as_float(b);
}
__device__ __forceinline__ void gload16(const void* g, void* l) {
    __builtin_amdgcn_global_load_lds(
        (const __attribute__((address_space(1))) void*)g,
        (__attribute__((address_space(3))) void*)l, 16, 0, 0);
}

// ---------- precompute: fused split of x (with norms) and emb (normalized) ----------
__global__ void split_all_kernel(const float* __restrict__ x, const float* __restrict__ emb,
                                 _Float16* __restrict__ xh, _Float16* __restrict__ xl,
                                 _Float16* __restrict__ eh, _Float16* __restrict__ el,
                                 float* __restrict__ xnorm, float* __restrict__ inv_norm) {
    int r4   = blockIdx.x * 4 + (threadIdx.x >> 6);
    int lane = threadIdx.x & 63;
    if (r4 < M_ROWS) {                       // x rows: split + row norm
        float4 v = reinterpret_cast<const float4*>(x + (size_t)r4 * DDIM)[lane];
        float s = v.x * v.x + v.y * v.y + v.z * v.z + v.w * v.w;
        #pragma unroll
        for (int m = 32; m; m >>= 1) s += __shfl_xor(s, m, 64);
        if (lane == 0) xnorm[r4] = sqrtf(s);
        float sv[4] = {v.x, v.y, v.z, v.w};
        half4v h, lo;
        #pragma unroll
        for (int j = 0; j < 4; ++j) {
            _Float16 hh = (_Float16)sv[j];
            h[j]  = hh;
            lo[j] = (_Float16)((sv[j] - (float)hh) * LSCALE);
        }
        *reinterpret_cast<half4v*>(xh + (size_t)r4 * DDIM + lane * 4) = h;
        *reinterpret_cast<half4v*>(xl + (size_t)r4 * DDIM + lane * 4) = lo;
    } else {                                 // emb rows: l2norm + split
        int row = r4 - M_ROWS;
        float4 v = reinterpret_cast<const float4*>(emb + (size_t)row * DDIM)[lane];
        float s = v.x * v.x + v.y * v.y + v.z * v.z + v.w * v.w;
        #pragma unroll
        for (int m = 32; m; m >>= 1) s += __shfl_xor(s, m, 64);
        float inv = 1.0f / fmaxf(sqrtf(s), 1e-12f);
        if (lane == 0) inv_norm[row] = inv;
        float sv[4] = {v.x * inv, v.y * inv, v.z * inv, v.w * inv};
        half4v h, lo;
        #pragma unroll
        for (int j = 0; j < 4; ++j) {
            _Float16 hh = (_Float16)sv[j];
            h[j]  = hh;
            lo[j] = (_Float16)((sv[j] - (float)hh) * LSCALE);
        }
        *reinterpret_cast<half4v*>(eh + (size_t)row * DDIM + lane * 4) = h;
        *reinterpret_cast<half4v*>(el + (size_t)row * DDIM + lane * 4) = lo;
    }
}

// ---------- pass1: hh-only MFMA GEMM, top-2 per row per split ----------
// LDS: [2 bufs][xh 128x32 | eh 128x32] = 32KB, proven 16B-slot swizzle.
// Cross-wx merge buffers kx/sx (3KB) are SEPARATE arrays -> no aliasing.
__global__ __launch_bounds__(256, 2)
void mfma1_kernel(const _Float16* __restrict__ xh, const _Float16* __restrict__ eh,
                  unsigned long long* __restrict__ partB, float* __restrict__ partS) {
    __shared__ _Float16 lds[2][2 * TILE_H];
    __shared__ unsigned long long kx[2][BR];   // [wx][row_local]
    __shared__ float              sx[2][BR];

    const int t  = threadIdx.x;
    const int l  = t & 63;
    const int w  = t >> 6;
    const int wy = w >> 1, wx = w & 1;
    const int rb = blockIdx.x * BR;
    const int split = blockIdx.y;
    const int cs = split * CPS;
    const int lr = l & 15;
    const int kg = l >> 4;

    const int s_row = l >> 2;
    const int s_kg  = (l & 3) ^ ((l >> 3) & 3);
    const int tl = w >> 1;                 // staged tile: 0=xh, 1=eh
    const int hf = w & 1;                  // row half 0..63 / 64..127
    const _Float16* gsrc = (tl == 0) ? xh : eh;
    const int srow_off = hf * 64 + s_row;

    const int rd_off = lr * 32 + (kg ^ ((lr >> 1) & 3)) * 8;
    const int a_base = wy * 2048 + rd_off;
    const int b_base = TILE_H + wx * 2048 + rd_off;

    float bestv[16], secv[16];
    unsigned int bestc[16];
    #pragma unroll
    for (int i = 0; i < 16; ++i) { bestv[i] = -1e30f; secv[i] = -1e30f; bestc[i] = 0; }

    f32x4 acc[4][4];

    {   // prologue: slice 0 staging (4 gloads/wave)
        const _Float16* gp = gsrc + (size_t)((tl == 0 ? rb : cs) + srow_off) * DDIM + s_kg * 8;
        _Float16* lp = &lds[0][tl * TILE_H + hf * 2048];
        #pragma unroll
        for (int c = 0; c < 4; ++c)
            gload16(gp + c * 16 * DDIM, lp + c * 512);
    }

    int buf = 0;
    #pragma unroll 1
    for (int st = 0; st < NSLICE; ++st) {
        const int cb = cs + (st >> 3) * BCC;

        if ((st & 7) == 0) {
            #pragma unroll
            for (int m = 0; m < 4; ++m)
                #pragma unroll
                for (int n = 0; n < 4; ++n)
                    acc[m][n] = (f32x4){0.f, 0.f, 0.f, 0.f};
        }

        if (st + 1 < NSLICE) {
            const int ncb = cs + ((st + 1) >> 3) * BCC;
            const int ndb = ((st + 1) & 7) * BK;
            const _Float16* gp = gsrc + (size_t)((tl == 0 ? rb : ncb) + srow_off) * DDIM
                                 + ndb + s_kg * 8;
            _Float16* lp = &lds[buf ^ 1][tl * TILE_H + hf * 2048];
            #pragma unroll
            for (int c = 0; c < 4; ++c)
                gload16(gp + c * 16 * DDIM, lp + c * 512);
            asm volatile("s_waitcnt vmcnt(4)" ::: "memory");
        } else {
            asm volatile("s_waitcnt vmcnt(0)" ::: "memory");
        }
        __builtin_amdgcn_s_barrier();
        __builtin_amdgcn_sched_barrier(0);

        const _Float16* L = lds[buf];
        half8v ah[4];
        #pragma unroll
        for (int m = 0; m < 4; ++m)
            ah[m] = *reinterpret_cast<const half8v*>(&L[a_base + m * 512]);
        __builtin_amdgcn_s_setprio(1);
        #pragma unroll
        for (int n = 0; n < 4; ++n) {
            half8v bh = *reinterpret_cast<const half8v*>(&L[b_base + n * 512]);
            #pragma unroll
            for (int m = 0; m < 4; ++m)
                acc[m][n] = __builtin_amdgcn_mfma_f32_16x16x32_f16(ah[m], bh, acc[m][n], 0, 0, 0);
        }
        __builtin_amdgcn_s_setprio(0);

        if ((st & 7) == 7) {   // fold chunk with top-2
            #pragma unroll
            for (int m = 0; m < 4; ++m)
                #pragma unroll
                for (int r = 0; r < 4; ++r) {
                    int bi = m * 4 + r;
                    #pragma unroll
                    for (int n = 0; n < 4; ++n) {
                        float v = acc[m][n][r];
                        unsigned int code = cb + wx * 64 + n * 16 + lr;
                        if (v > bestv[bi]) { secv[bi] = bestv[bi]; bestv[bi] = v; bestc[bi] = code; }
                        else if (v > secv[bi]) secv[bi] = v;
                    }
                }
        }

        __builtin_amdgcn_sched_barrier(0);
        __builtin_amdgcn_s_barrier();
        buf ^= 1;
    }

    // reduce (b,s,c) across the 16 code-columns (lane bits 0..3)
    #pragma unroll
    for (int mb = 1; mb < 16; mb <<= 1) {
        #pragma unroll
        for (int i = 0; i < 16; ++i) {
            float ob        = __shfl_xor(bestv[i], mb, 64);
            float os        = __shfl_xor(secv[i],  mb, 64);
            unsigned int oc = __shfl_xor(bestc[i], mb, 64);
            if (ob > bestv[i] || (ob == bestv[i] && oc < bestc[i])) {
                secv[i]  = fmaxf(bestv[i], os);
                bestv[i] = ob; bestc[i] = oc;
            } else {
                secv[i] = fmaxf(secv[i], ob);
            }
        }
    }

    // cross-wx merge via LDS (fixes R9's write race): each wave deposits its
    // per-row (key, sec); threads 0..127 merge the two code-halves exactly.
    if (lr == 0) {
        #pragma unroll
        for (int m = 0; m < 4; ++m)
            #pragma unroll
            for (int r = 0; r < 4; ++r) {
                int row_local = wy * 64 + m * 16 + (l >> 4) * 4 + r;
                int bi = m * 4 + r;
                kx[wx][row_local] = ((unsigned long long)fkey(bestv[bi]) << 32) |
                                    (unsigned long long)(0xFFFFFFFFu - bestc[bi]);
                sx[wx][row_local] = secv[bi];
            }
    }
    __syncthreads();
    if (t < BR) {
        unsigned long long k0 = kx[0][t], k1 = kx[1][t];
        float s0 = sx[0][t], s1 = sx[1][t];
        unsigned long long gb;
        float gs;
        if (k1 > k0) { gb = k1; gs = fmaxf(s1, fkey_dec(k0)); }
        else         { gb = k0; gs = fmaxf(s0, fkey_dec(k1)); }
        partB[(size_t)(rb + t) * NSPLIT + split] = gb;
        partS[(size_t)(rb + t) * NSPLIT + split] = gs;
    }
}

// ---------- merge: global top-2 per row, margin test, compact rescue list ----------
__global__ void merge_kernel(const unsigned long long* __restrict__ partB,
                             const float* __restrict__ partS,
                             const float* __restrict__ xnorm,
                             unsigned long long* __restrict__ best,
                             int* __restrict__ cnt, int* __restrict__ list) {
    int row = blockIdx.x * 256 + threadIdx.x;
    const unsigned long long* pB = partB + (size_t)row * NSPLIT;
    const float* pS = partS + (size_t)row * NSPLIT;

    unsigned long long gbk = pB[0];
    float sown = pS[0];
    float gs = -1e30f;
    #pragma unroll
    for (int s = 1; s < NSPLIT; ++s) {
        unsigned long long k = pB[s];
        if (k > gbk) { gs = fmaxf(gs, fkey_dec(gbk)); gbk = k; sown = pS[s]; }
        else         { gs = fmaxf(gs, fkey_dec(k)); }
    }
    gs = fmaxf(gs, sown);
    float gbv = fkey_dec(gbk);

    float margin = MARGIN_COEF * xnorm[row];
    if (gbv - gs < margin) {
        int p = atomicAdd(cnt, 1);
        list[p] = row;
        best[row] = 0ULL;           // pass2 atomicMax fills in
    } else {
        best[row] = gbk;            // provably the exact argmax
    }
}

// ---------- pass2: 3-term exact on rescued rows (gathered) ----------
// LDS: [2][ xh 64x32 | xl 64x32 | eh 128x32 | el 128x32 ] = 48KB.
#define XH0 0
#define XL0 2048
#define EH0 4096
#define EL0 8192

__global__ __launch_bounds__(256, 2)
void mfma2_kernel(const _Float16* __restrict__ xh, const _Float16* __restrict__ xl,
                  const _Float16* __restrict__ eh, const _Float16* __restrict__ el,
                  const int* __restrict__ cntp, const int* __restrict__ list,
                  unsigned long long* __restrict__ best) {
    const int cnt = *cntp;
    const int rb2 = blockIdx.x;                 // 64-row group in the list
    if (rb2 * BR2 >= cnt) return;               // uniform early exit (no barriers yet)

    __shared__ _Float16 lds[2][12288];

    const int t  = threadIdx.x;
    const int l  = t & 63;
    const int w  = t >> 6;
    const int wy = w >> 1, wx = w & 1;          // wave tile 32 rows x 64 codes
    const int cs2 = blockIdx.y * CPS2;
    const int lr = l & 15;
    const int kg = l >> 4;

    const int s_row = l >> 2;
    const int s_kg  = (l & 3) ^ ((l >> 3) & 3);

    const int rd_off = lr * 32 + (kg ^ ((lr >> 1) & 3)) * 8;

    // gathered row indices for staging (waves 0,1) — 4 chunk-rows per lane
    int ridx[4];
    if (w < 2) {
        #pragma unroll
        for (int c = 0; c < 4; ++c) {
            int p = rb2 * BR2 + c * 16 + s_row;
            ridx[c] = list[min(p, cnt - 1)];
        }
    }

    float bestv[8];
    unsigned int bestc[8];
    #pragma unroll
    for (int i = 0; i < 8; ++i) { bestv[i] = -1e30f; bestc[i] = 0; }

    f32x4 acc[2][4], acc2[2][4];

    {   // prologue: slice 0
        if (w == 0) {
            #pragma unroll
            for (int c = 0; c < 4; ++c)
                gload16(xh + (size_t)ridx[c] * DDIM + s_kg * 8, &lds[0][XH0 + c * 512]);
        } else if (w == 1) {
            #pragma unroll
            for (int c = 0; c < 4; ++c)
                gload16(xl + (size_t)ridx[c] * DDIM + s_kg * 8, &lds[0][XL0 + c * 512]);
        } else if (w == 2) {
            #pragma unroll
            for (int c = 0; c < 8; ++c)
                gload16(eh + (size_t)(cs2 + c * 16 + s_row) * DDIM + s_kg * 8,
                        &lds[0][EH0 + c * 512]);
        } else {
            #pragma unroll
            for (int c = 0; c < 8; ++c)
                gload16(el + (size_t)(cs2 + c * 16 + s_row) * DDIM + s_kg * 8,
                        &lds[0][EL0 + c * 512]);
        }
    }

    int buf = 0;
    #pragma unroll 1
    for (int st = 0; st < NSLICE2; ++st) {
        const int cb = cs2 + (st >> 3) * BCC;

        if ((st & 7) == 0) {
            #pragma unroll
            for (int m = 0; m < 2; ++m)
                #pragma unroll
                for (int n = 0; n < 4; ++n) {
                    acc[m][n]  = (f32x4){0.f, 0.f, 0.f, 0.f};
                    acc2[m][n] = (f32x4){0.f, 0.f, 0.f, 0.f};
                }
        }

        if (st + 1 < NSLICE2) {
            const int ncb = cs2 + ((st + 1) >> 3) * BCC;
            const int ndb = ((st + 1) & 7) * BK;
            _Float16* lb = lds[buf ^ 1];
            if (w == 0) {
                #pragma unroll
                for (int c = 0; c < 4; ++c)
                    gload16(xh + (size_t)ridx[c] * DDIM + ndb + s_kg * 8, lb + XH0 + c * 512);
            } else if (w == 1) {
                #pragma unroll
                for (int c = 0; c < 4; ++c)
                    gload16(xl + (size_t)ridx[c] * DDIM + ndb + s_kg * 8, lb + XL0 + c * 512);
            } else if (w == 2) {
                #pragma unroll
                for (int c = 0; c < 8; ++c)
                    gload16(eh + (size_t)(ncb + c * 16 + s_row) * DDIM + ndb + s_kg * 8,
                            lb + EH0 + c * 512);
            } else {
                #pragma unroll
                for (int c = 0; c < 8; ++c)
                    gload16(el + (size_t)(ncb + c * 16 + s_row) * DDIM + ndb + s_kg * 8,
                            lb + EL0 + c * 512);
            }
            if (w < 2) asm volatile("s_waitcnt vmcnt(4)" ::: "memory");
            else       asm volatile("s_waitcnt vmcnt(8)" ::: "memory");
        } else {
            asm volatile("s_waitcnt vmcnt(0)" ::: "memory");
        }
        __builtin_amdgcn_s_barrier();
        __builtin_amdgcn_sched_barrier(0);

        const _Float16* L = lds[buf];
        half8v ah[2], al[2];
        #pragma unroll
        for (int m = 0; m < 2; ++m) {
            int ao = wy * 1024 + m * 512 + rd_off;
            ah[m] = *reinterpret_cast<const half8v*>(&L[XH0 + ao]);
            al[m] = *reinterpret_cast<const half8v*>(&L[XL0 + ao]);
        }
        __builtin_amdgcn_s_setprio(1);
        #pragma unroll
        for (int n = 0; n < 4; ++n) {
            int bo = wx * 2048 + n * 512 + rd_off;
            half8v bh = *reinterpret_cast<const half8v*>(&L[EH0 + bo]);
            half8v bl = *reinterpret_cast<const half8v*>(&L[EL0 + bo]);
            #pragma unroll
            for (int m = 0; m < 2; ++m) {
                acc[m][n]  = __builtin_amdgcn_mfma_f32_16x16x32_f16(ah[m], bh, acc[m][n],  0, 0, 0);
                acc2[m][n] = __builtin_amdgcn_mfma_f32_16x16x32_f16(ah[m], bl, acc2[m][n], 0, 0, 0);
                acc2[m][n] = __builtin_amdgcn_mfma_f32_16x16x32_f16(al[m], bh, acc2[m][n], 0, 0, 0);
            }
        }
        __builtin_amdgcn_s_setprio(0);

        if ((st & 7) == 7) {
            #pragma unroll
            for (int m = 0; m < 2; ++m)
                #pragma unroll
                for (int r = 0; r < 4; ++r) {
                    int bi = m * 4 + r;
                    #pragma unroll
                    for (int n = 0; n < 4; ++n) {
                        float v = acc[m][n][r] + acc2[m][n][r] * INV_LSCALE;
                        unsigned int code = cb + wx * 64 + n * 16 + lr;
                        if (v > bestv[bi]) { bestv[bi] = v; bestc[bi] = code; }
                    }
                }
        }

        __builtin_amdgcn_sched_barrier(0);
        __builtin_amdgcn_s_barrier();
        buf ^= 1;
    }

    #pragma unroll
    for (int mb = 1; mb < 16; mb <<= 1) {
        #pragma unroll
        for (int i = 0; i < 8; ++i) {
            float ov        = __shfl_xor(bestv[i], mb, 64);
            unsigned int oc = __shfl_xor(bestc[i], mb, 64);
            if (ov > bestv[i] || (ov == bestv[i] && oc < bestc[i])) {
                bestv[i] = ov; bestc[i] = oc;
            }
        }
    }
    if (lr == 0) {
        #pragma unroll
        for (int m = 0; m < 2; ++m)
            #pragma unroll
            for (int r = 0; r < 4; ++r) {
                int p = rb2 * BR2 + wy * 32 + m * 16 + (l >> 4) * 4 + r;
                if (p < cnt) {
                    int bi = m * 4 + r;
                    unsigned long long key =
                        ((unsigned long long)fkey(bestv[bi]) << 32) |
                        (unsigned long long)(0xFFFFFFFFu - bestc[bi]);
                    atomicMax(&best[list[p]], key);
                }
            }
    }
}

// ---------- tier-2 main (R8, proven): 3-term everywhere ----------
__global__ __launch_bounds__(256, 2)
void mfma3p_kernel(const _Float16* __restrict__ xh, const _Float16* __restrict__ xl,
                   const _Float16* __restrict__ eh, const _Float16* __restrict__ el,
                   unsigned long long* __restrict__ best) {
    __shared__ _Float16 lds[2][4 * TILE_H];
    const int t = threadIdx.x, l = t & 63, w = t >> 6;
    const int wy = w >> 1, wx = w & 1;
    const int rb = blockIdx.x * BR, cs = blockIdx.y * CPS;
    const int lr = l & 15, kg = l >> 4;
    const int s_row = l >> 2, s_kg = (l & 3) ^ ((l >> 3) & 3);
    const int rd_off = lr * 32 + (kg ^ ((lr >> 1) & 3)) * 8;
    const int a_base = wy * 64 * 32 + rd_off;
    const int b_base = wx * 64 * 32 + rd_off;
    const _Float16* gsrc = (w == 0) ? xh : (w == 1) ? xl : (w == 2) ? eh : el;
    const int g_is_x = (w < 2);
    float bestv[16]; unsigned int bestc[16];
    #pragma unroll
    for (int i = 0; i < 16; ++i) { bestv[i] = -1e30f; bestc[i] = 0; }
    f32x4 acc[4][4], acc2[4][4];
    {
        const _Float16* gp = gsrc + (size_t)((g_is_x ? rb : cs) + s_row) * DDIM + s_kg * 8;
        _Float16* lp = &lds[0][w * TILE_H];
        #pragma unroll
        for (int c = 0; c < 8; ++c) gload16(gp + c * 16 * DDIM, lp + c * 512);
    }
    int buf = 0;
    #pragma unroll 1
    for (int st = 0; st < NSLICE; ++st) {
        const int cb = cs + (st >> 3) * BCC;
        if ((st & 7) == 0) {
            #pragma unroll
            for (int m = 0; m < 4; ++m)
                #pragma unroll
                for (int n = 0; n < 4; ++n) {
                    acc[m][n] = (f32x4){0.f,0.f,0.f,0.f}; acc2[m][n] = (f32x4){0.f,0.f,0.f,0.f};
                }
        }
        if (st + 1 < NSLICE) {
            const int ncb = cs + ((st + 1) >> 3) * BCC;
            const int ndb = ((st + 1) & 7) * BK;
            const _Float16* gp = gsrc + (size_t)((g_is_x ? rb : ncb) + s_row) * DDIM + ndb + s_kg * 8;
            _Float16* lp = &lds[buf ^ 1][w * TILE_H];
            #pragma unroll
            for (int c = 0; c < 8; ++c) gload16(gp + c * 16 * DDIM, lp + c * 512);
            asm volatile("s_waitcnt vmcnt(8)" ::: "memory");
        } else {
            asm volatile("s_waitcnt vmcnt(0)" ::: "memory");
        }
        __builtin_amdgcn_s_barrier();
        __builtin_amdgcn_sched_barrier(0);
        const _Float16* L = lds[buf];
        half8v ah[4], al[4];
        #pragma unroll
        for (int m = 0; m < 4; ++m) {
            ah[m] = *reinterpret_cast<const half8v*>(&L[0 * TILE_H + a_base + m * 512]);
            al[m] = *reinterpret_cast<const half8v*>(&L[1 * TILE_H + a_base + m * 512]);
        }
        __builtin_amdgcn_s_setprio(1);
        #pragma unroll
        for (int n = 0; n < 4; ++n) {
            half8v bh = *reinterpret_cast<const half8v*>(&L[2 * TILE_H + b_base + n * 512]);
            half8v bl = *reinterpret_cast<const half8v*>(&L[3 * TILE_H + b_base + n * 512]);
            #pragma unroll
            for (int m = 0; m < 4; ++m) {
                acc[m][n]  = __builtin_amdgcn_mfma_f32_16x16x32_f16(ah[m], bh, acc[m][n],  0, 0, 0);
                acc2[m][n] = __builtin_amdgcn_mfma_f32_16x16x32_f16(ah[m], bl, acc2[m][n], 0, 0, 0);
                acc2[m][n] = __builtin_amdgcn_mfma_f32_16x16x32_f16(al[m], bh, acc2[m][n], 0, 0, 0);
            }
        }
        __builtin_amdgcn_s_setprio(0);
        if ((st & 7) == 7) {
            #pragma unroll
            for (int m = 0; m < 4; ++m)
                #pragma unroll
                for (int r = 0; r < 4; ++r) {
                    int bi = m * 4 + r;
                    #pragma unroll
                    for (int n = 0; n < 4; ++n) {
                        float v = acc[m][n][r] + acc2[m][n][r] * INV_LSCALE;
                        unsigned int code = cb + wx * 64 + n * 16 + lr;
                        if (v > bestv[bi]) { bestv[bi] = v; bestc[bi] = code; }
                    }
                }
        }
        __builtin_amdgcn_sched_barrier(0);
        __builtin_amdgcn_s_barrier();
        buf ^= 1;
    }
    #pragma unroll
    for (int mb = 1; mb < 16; mb <<= 1) {
        #pragma unroll
        for (int i = 0; i < 16; ++i) {
            float ov = __shfl_xor(bestv[i], mb, 64);
            unsigned int oc = __shfl_xor(bestc[i], mb, 64);
            if (ov > bestv[i] || (ov == bestv[i] && oc < bestc[i])) { bestv[i] = ov; bestc[i] = oc; }
        }
    }
    if (lr == 0) {
        #pragma unroll
        for (int m = 0; m < 4; ++m)
            #pragma unroll
            for (int r = 0; r < 4; ++r) {
                int row_global = rb + wy * 64 + m * 16 + (l >> 4) * 4 + r;
                int bi = m * 4 + r;
                unsigned long long key = ((unsigned long long)fkey(bestv[bi]) << 32) |
                                         (unsigned long long)(0xFFFFFFFFu - bestc[bi]);
                atomicMax(&best[row_global], key);
            }
    }
}

// ---------- tier-3 fallback (R4, proven) ----------
#define LDP  (BK + 8)
__device__ __forceinline__ void split4(float a, float b, float c, float d,
                                       half4v& h, half4v& lo) {
    h[0] = (_Float16)a; lo[0] = (_Float16)((a - (float)h[0]) * LSCALE);
    h[1] = (_Float16)b; lo[1] = (_Float16)((b - (float)h[1]) * LSCALE);
    h[2] = (_Float16)c; lo[2] = (_Float16)((c - (float)h[2]) * LSCALE);
    h[3] = (_Float16)d; lo[3] = (_Float16)((d - (float)h[3]) * LSCALE);
}
__global__ void norm_emb_kernel(const float* __restrict__ emb, float* __restrict__ inv_norm) {
    int row  = blockIdx.x * 4 + (threadIdx.x >> 6);
    int lane = threadIdx.x & 63;
    float4 v = reinterpret_cast<const float4*>(emb + (size_t)row * DDIM)[lane];
    float s = v.x * v.x + v.y * v.y + v.z * v.z + v.w * v.w;
    #pragma unroll
    for (int m = 32; m; m >>= 1) s += __shfl_xor(s, m, 64);
    if (lane == 0) inv_norm[row] = 1.0f / fmaxf(sqrtf(s), 1e-12f);
}
__global__ __launch_bounds__(256, 2)
void mfma_argmax_fb(const float* __restrict__ x, const float* __restrict__ emb,
                    const float* __restrict__ invn, unsigned long long* __restrict__ best) {
    __shared__ _Float16 Ah[BR][LDP];
    __shared__ _Float16 Al[BR][LDP];
    __shared__ _Float16 Bh[BCC][LDP];
    __shared__ _Float16 Bl[BCC][LDP];
    const int t = threadIdx.x, l = t & 63, wid = t >> 6;
    const int wy = wid >> 1, wx = wid & 1;
    const int rb = blockIdx.x * BR, cs = blockIdx.y * CPS;
    const int lr = l & 15, lk = (l >> 4) * 8;
    const int srow = t >> 3, sc4 = (t & 7) * 4;
    float bestv[16]; unsigned int bestc[16];
    #pragma unroll
    for (int i = 0; i < 16; ++i) { bestv[i] = -1e30f; bestc[i] = 0; }
    #pragma unroll 1
    for (int cc = 0; cc < CPS; cc += BCC) {
        const int cb = cs + cc;
        float bn[4];
        #pragma unroll
        for (int it = 0; it < 4; ++it) bn[it] = invn[cb + srow + it * 32];
        f32x4 acc[4][4], acc2[4][4];
        #pragma unroll
        for (int m = 0; m < 4; ++m)
            #pragma unroll
            for (int n = 0; n < 4; ++n) {
                acc[m][n] = (f32x4){0.f,0.f,0.f,0.f}; acc2[m][n] = (f32x4){0.f,0.f,0.f,0.f};
            }
        #pragma unroll 1
        for (int db = 0; db < DDIM; db += BK) {
            __syncthreads();
            #pragma unroll
            for (int it = 0; it < 4; ++it) {
                int row = srow + it * 32;
                float4 av = *reinterpret_cast<const float4*>(x + (size_t)(rb + row) * DDIM + db + sc4);
                half4v h, lo;
                split4(av.x, av.y, av.z, av.w, h, lo);
                *reinterpret_cast<half4v*>(&Ah[row][sc4]) = h;
                *reinterpret_cast<half4v*>(&Al[row][sc4]) = lo;
                float4 bv = *reinterpret_cast<const float4*>(emb + (size_t)(cb + row) * DDIM + db + sc4);
                float s = bn[it];
                split4(bv.x * s, bv.y * s, bv.z * s, bv.w * s, h, lo);
                *reinterpret_cast<half4v*>(&Bh[row][sc4]) = h;
                *reinterpret_cast<half4v*>(&Bl[row][sc4]) = lo;
            }
            __syncthreads();
            half8v ah[4], al[4];
            #pragma unroll
            for (int m = 0; m < 4; ++m) {
                ah[m] = *reinterpret_cast<const half8v*>(&Ah[wy * 64 + m * 16 + lr][lk]);
                al[m] = *reinterpret_cast<const half8v*>(&Al[wy * 64 + m * 16 + lr][lk]);
            }
            #pragma unroll
            for (int n = 0; n < 4; ++n) {
                half8v bh = *reinterpret_cast<const half8v*>(&Bh[wx * 64 + n * 16 + lr][lk]);
                half8v bl = *reinterpret_cast<const half8v*>(&Bl[wx * 64 + n * 16 + lr][lk]);
                #pragma unroll
                for (int m = 0; m < 4; ++m) {
                    acc[m][n]  = __builtin_amdgcn_mfma_f32_16x16x32_f16(ah[m], bh, acc[m][n],  0, 0, 0);
                    acc2[m][n] = __builtin_amdgcn_mfma_f32_16x16x32_f16(ah[m], bl, acc2[m][n], 0, 0, 0);
                    acc2[m][n] = __builtin_amdgcn_mfma_f32_16x16x32_f16(al[m], bh, acc2[m][n], 0, 0, 0);
                }
            }
        }
        #pragma unroll
        for (int m = 0; m < 4; ++m)
            #pragma unroll
            for (int r = 0; r < 4; ++r) {
                int bi = m * 4 + r;
                #pragma unroll
                for (int n = 0; n < 4; ++n) {
                    float v = acc[m][n][r] + acc2[m][n][r] * INV_LSCALE;
                    unsigned int code = cb + wx * 64 + n * 16 + lr;
                    if (v > bestv[bi]) { bestv[bi] = v; bestc[bi] = code; }
                }
            }
    }
    #pragma unroll
    for (int mb = 1; mb < 16; mb <<= 1) {
        #pragma unroll
        for (int i = 0; i < 16; ++i) {
            float ov = __shfl_xor(bestv[i], mb, 64);
            unsigned int oc = __shfl_xor(bestc[i], mb, 64);
            if (ov > bestv[i] || (ov == bestv[i] && oc < bestc[i])) { bestv[i] = ov; bestc[i] = oc; }
        }
    }
    if (lr == 0) {
        #pragma unroll
        for (int m = 0; m < 4; ++m)
            #pragma unroll
            for (int r = 0; r < 4; ++r) {
                int row_global = rb + wy * 64 + m * 16 + (l >> 4) * 4 + r;
                int bi = m * 4 + r;
                unsigned long long key = ((unsigned long long)fkey(bestv[bi]) << 32) |
                                         (unsigned long long)(0xFFFFFFFFu - bestc[bi]);
                atomicMax(&best[row_global], key);
            }
    }
}

// gather un-normalized embedding rows + write indices as float (4 rows/block)
__global__ void finalize_kernel(const unsigned long long* __restrict__ best,
                                const float* __restrict__ emb,
                                float* __restrict__ out) {
    int row  = blockIdx.x * 4 + (threadIdx.x >> 6);
    int lane = threadIdx.x & 63;
    unsigned long long b = best[row];
    unsigned int code = 0xFFFFFFFFu - (unsigned int)(b & 0xFFFFFFFFull);
    float4 v = reinterpret_cast<const float4*>(emb + (size_t)code * DDIM)[lane];
    reinterpret_cast<float4*>(out + (size_t)row * DDIM)[lane] = v;
    if (lane == 0) out[(size_t)M_ROWS * DDIM + row] = (float)code;
}

extern "C" void kernel_launch(void* const* d_in, const int* in_sizes, int n_in,
                              void* d_out, int out_size, void* d_ws, size_t ws_size,
                              hipStream_t stream) {
    const float* x   = (const float*)d_in[0];
    const float* emb = (const float*)d_in[1];
    float* out = (float*)d_out;
    char* ws = (char*)d_ws;

    const size_t xbytes = (size_t)M_ROWS * DDIM * sizeof(_Float16);   // 8MB
    const size_t ebytes = (size_t)KCODES * DDIM * sizeof(_Float16);   // 4MB

    // tier-1 layout
    unsigned long long* best  = (unsigned long long*)ws;              // 128KB
    float*              invn  = (float*)(ws + 128 * 1024);            // 32KB
    float*              xnorm = (float*)(ws + 160 * 1024);            // 64KB
    int*                cnt   = (int*)(ws + 224 * 1024);
    int*                list  = (int*)(ws + 228 * 1024);              // 64KB
    unsigned long long* partB = (unsigned long long*)(ws + 512 * 1024);   // 1MB
    float*              partS = (float*)(ws + 1536 * 1024);           // 512KB
    _Float16* xh1 = (_Float16*)(ws + 2 * 1024 * 1024);
    _Float16* xl1 = (_Float16*)((char*)xh1 + xbytes);
    _Float16* eh1 = (_Float16*)((char*)xl1 + xbytes);
    _Float16* el1 = (_Float16*)((char*)eh1 + ebytes);
    const size_t need1 = 2 * 1024 * 1024 + 2 * xbytes + 2 * ebytes;   // ~26MB

    // tier-2 layout (R8)
    const size_t split_off = 160 * 1024;
    const size_t need2 = split_off + 2 * xbytes + 2 * ebytes;

    if (ws_size >= need1) {
        hipMemsetAsync(cnt, 0, sizeof(int), stream);
        split_all_kernel<<<(M_ROWS + KCODES) / 4, 256, 0, stream>>>(
            x, emb, xh1, xl1, eh1, el1, xnorm, invn);
        mfma1_kernel<<<dim3(M_ROWS / BR, NSPLIT), 256, 0, stream>>>(xh1, eh1, partB, partS);
        merge_kernel<<<M_ROWS / 256, 256, 0, stream>>>(partB, partS, xnorm, best, cnt, list);
        mfma2_kernel<<<dim3(M_ROWS / BR2, NSPLIT2), 256, 0, stream>>>(
            xh1, xl1, eh1, el1, cnt, list, best);
    } else if (ws_size >= need2) {
        _Float16* xh = (_Float16*)(ws + split_off);
        _Float16* xl = (_Float16*)((char*)xh + xbytes);
        _Float16* eh = (_Float16*)((char*)xl + xbytes);
        _Float16* el = (_Float16*)((char*)eh + ebytes);
        hipMemsetAsync(best, 0, M_ROWS * sizeof(unsigned long long), stream);
        split_all_kernel<<<(M_ROWS + KCODES) / 4, 256, 0, stream>>>(
            x, emb, xh, xl, eh, el, invn /*reuse as xnorm dump*/, invn);
        mfma3p_kernel<<<dim3(M_ROWS / BR, NSPLIT), 256, 0, stream>>>(xh, xl, eh, el, best);
    } else {
        hipMemsetAsync(best, 0, M_ROWS * sizeof(unsigned long long), stream);
        norm_emb_kernel<<<KCODES / 4, 256, 0, stream>>>(emb, invn);
        mfma_argmax_fb<<<dim3(M_ROWS / BR, NSPLIT), 256, 0, stream>>>(x, emb, invn, best);
    }
    finalize_kernel<<<M_ROWS / 4, 256, 0, stream>>>(best, emb, out);
}